// Round 18
// baseline (33.252 us; speedup 1.0000x reference)
//
#include <hip/hip_runtime.h>
#include <hip/hip_fp16.h>

typedef _Float16 f16x8 __attribute__((ext_vector_type(8)));
typedef _Float16 f16x2 __attribute__((ext_vector_type(2)));
typedef float f32x4 __attribute__((ext_vector_type(4)));

namespace {
constexpr int K = 4096;
constexpr int N = 11008;
constexpr int NC = N / 8;            // 1376 packed words per K-row
constexpr int KSPLIT = 16;           // 256-deep K slices (2 quant groups)
constexpr int SLICE_K = K / KSPLIT;  // 256
constexpr int BN = 128;              // output columns per block (4 waves x 32)
constexpr int BK = 32;               // K rows per MFMA step
constexpr int NT = SLICE_K / BK;     // 8 steps
constexpr int QS = SLICE_K + 4;      // q LDS col stride, words (260)
constexpr int OUT_ELEMS = 32 * N;    // 352256
}

// x (f32) -> f16 (RTN) into workspace, once per call
__global__ void cvt_x_kernel(const float* __restrict__ x, _Float16* __restrict__ xh) {
  const int i = (blockIdx.x * 256 + threadIdx.x) * 8;
  const float4 v0 = *reinterpret_cast<const float4*>(x + i);
  const float4 v1 = *reinterpret_cast<const float4*>(x + i + 4);
  f16x8 h;
  h[0] = (_Float16)v0.x; h[1] = (_Float16)v0.y;
  h[2] = (_Float16)v0.z; h[3] = (_Float16)v0.w;
  h[4] = (_Float16)v1.x; h[5] = (_Float16)v1.y;
  h[6] = (_Float16)v1.z; h[7] = (_Float16)v1.w;
  *reinterpret_cast<f16x8*>(xh + i) = h;
}

// sum 16 f16 K-slice partials + bias -> out (8 outputs per thread)
__global__ void reduce_kernel(const _Float16* __restrict__ partial,
                              const float* __restrict__ bias,
                              float* __restrict__ out) {
  const int idx = (blockIdx.x * 256 + threadIdx.x) * 8;   // 172 blocks exact
  const int n = idx % N;                                  // N, idx multiples of 8
  const float4 b0 = *reinterpret_cast<const float4*>(bias + n);
  const float4 b1 = *reinterpret_cast<const float4*>(bias + n + 4);
  float a[8] = {b0.x, b0.y, b0.z, b0.w, b1.x, b1.y, b1.z, b1.w};
#pragma unroll
  for (int s = 0; s < KSPLIT; ++s) {
    const f16x8 p = *reinterpret_cast<const f16x8*>(partial + (long)s * OUT_ELEMS + idx);
#pragma unroll
    for (int j = 0; j < 8; ++j) a[j] += (float)p[j];
  }
  float4 o0 = {a[0], a[1], a[2], a[3]}, o1 = {a[4], a[5], a[6], a[7]};
  *reinterpret_cast<float4*>(out + idx)     = o0;
  *reinterpret_cast<float4*>(out + idx + 4) = o1;
}

// q-only LDS (16.6 KB -> 8 blocks/CU resident); A-fragments stream from the
// L2-hot f16 workspace with 1-step register prefetch. One barrier total.
__global__ __launch_bounds__(256, 8) void awq_gemm_kernel(
    const int* __restrict__ qw, const int* __restrict__ qz,
    const float* __restrict__ sc, const _Float16* __restrict__ xh,
    _Float16* __restrict__ partial)
{
  __shared__ int lqs[16 * QS];   // q tile, col-major [col][k]

  const int tid  = threadIdx.x;
  const int lane = tid & 63;
  const int wid  = tid >> 6;      // wave 0..3
  const int kq   = lane >> 4;     // 0..3  (k-quarter within MFMA frag)
  const int c16  = lane & 15;     // fragment row/col index

  const int bx = blockIdx.x, by = blockIdx.y;
  const int n0 = bx * BN;
  const int c0 = n0 >> 3;

  // AWQ nibble shift for col (n&7): 4*AWQ_ORDER[n&7], order [0,4,1,5,2,6,3,7]
  const int j7 = c16 & 7;
  const int sh = ((j7 >> 1) | ((j7 & 1) << 2)) << 2;

  int ncol[2], cglob[2], cloc[2];
#pragma unroll
  for (int t2 = 0; t2 < 2; ++t2) {
    ncol[t2]  = n0 + wid * 32 + t2 * 16 + c16;
    cglob[t2] = ncol[t2] >> 3;
    cloc[t2]  = wid * 4 + t2 * 2 + (c16 >> 3);   // local word-col 0..15
  }

  const int kbeg = by * SLICE_K;
  const int g0   = kbeg >> 7;     // first of 2 quant groups in this slice

  // ---- q: one-shot fully-coalesced staging (4 dwordx4 per thread) ----
  const int qr = tid >> 2;        // 0..63
  const int wc = (tid & 3) * 4;   // 0,4,8,12
  int4 qv[4];
#pragma unroll
  for (int rr = 0; rr < 4; ++rr)
    qv[rr] = *reinterpret_cast<const int4*>(
        qw + (long)(kbeg + rr * 64 + qr) * NC + c0 + wc);

  // group scalars -> packed f16 constants (while q loads are in flight)
  f16x2 s2[2][2], mz2[2][2];      // [group][n-tile]
#pragma unroll
  for (int g = 0; g < 2; ++g)
#pragma unroll
    for (int t2 = 0; t2 < 2; ++t2) {
      const int zq = qz[(g0 + g) * NC + cglob[t2]];
      const _Float16 s16 = (_Float16)sc[(g0 + g) * N + ncol[t2]];
      const _Float16 mz  = (_Float16)(-(float)(1024 + ((zq >> sh) & 15)));
      s2[g][t2][0] = s16; s2[g][t2][1] = s16;
      mz2[g][t2][0] = mz; mz2[g][t2][1] = mz;
    }

  // ---- LDS writes (transpose to [col][k]; 2-way bank alias only) ----
#pragma unroll
  for (int rr = 0; rr < 4; ++rr) {
    const int r = rr * 64 + qr;
    lqs[(wc + 0) * QS + r] = qv[rr].x;
    lqs[(wc + 1) * QS + r] = qv[rr].y;
    lqs[(wc + 2) * QS + r] = qv[rr].z;
    lqs[(wc + 3) * QS + r] = qv[rr].w;
  }

  // A prefetch (regs), 1 step ahead, from L2-hot xh
  const _Float16* xbase = xh + kbeg + kq * 8;
  f16x8 areg[2][2];               // [slot][m-tile]
  areg[0][0] = *reinterpret_cast<const f16x8*>(xbase + c16 * K);
  areg[0][1] = *reinterpret_cast<const f16x8*>(xbase + (c16 + 16) * K);

  __syncthreads();               // the ONLY barrier

  f32x4 acc[2][2] = {};          // [m-tile][n-tile]

#pragma unroll
  for (int t = 0; t < NT; ++t) {
    const int cur = t & 1;
    if (t < NT - 1) {
      areg[cur ^ 1][0] = *reinterpret_cast<const f16x8*>(xbase + (t + 1) * BK + c16 * K);
      areg[cur ^ 1][1] = *reinterpret_cast<const f16x8*>(xbase + (t + 1) * BK + (c16 + 16) * K);
    }
    const int g = t >> 2;        // quant group (4 steps/group)

#pragma unroll
    for (int t2 = 0; t2 < 2; ++t2) {
      const int base = cloc[t2] * QS + t * BK + kq * 8;
      f16x8 b;
#pragma unroll
      for (int half = 0; half < 2; ++half) {
        const int4 q4 = *reinterpret_cast<const int4*>(&lqs[base + 4 * half]);
        const unsigned v0 = __builtin_amdgcn_ubfe((unsigned)q4.x, sh, 4);
        const unsigned v1 = __builtin_amdgcn_ubfe((unsigned)q4.y, sh, 4);
        const unsigned v2 = __builtin_amdgcn_ubfe((unsigned)q4.z, sh, 4);
        const unsigned v3 = __builtin_amdgcn_ubfe((unsigned)q4.w, sh, 4);
        const f16x2 h01 = __builtin_bit_cast(f16x2, (v0 | (v1 << 16)) | 0x64006400u);
        const f16x2 h23 = __builtin_bit_cast(f16x2, (v2 | (v3 << 16)) | 0x64006400u);
        const f16x2 w01 = (h01 + mz2[g][t2]) * s2[g][t2];   // exact (v-z), 1 rnd
        const f16x2 w23 = (h23 + mz2[g][t2]) * s2[g][t2];
        b[4 * half]     = w01[0];
        b[4 * half + 1] = w01[1];
        b[4 * half + 2] = w23[0];
        b[4 * half + 3] = w23[1];
      }
      acc[0][t2] = __builtin_amdgcn_mfma_f32_16x16x32_f16(areg[cur][0], b, acc[0][t2], 0, 0, 0);
      acc[1][t2] = __builtin_amdgcn_mfma_f32_16x16x32_f16(areg[cur][1], b, acc[1][t2], 0, 0, 0);
    }
  }

  // ---- epilogue: f16 partials, plain stores ----
  _Float16* pp = partial + (long)by * OUT_ELEMS;
#pragma unroll
  for (int mt = 0; mt < 2; ++mt)
#pragma unroll
    for (int t2 = 0; t2 < 2; ++t2)
#pragma unroll
      for (int i = 0; i < 4; ++i) {
        const int row = mt * 16 + kq * 4 + i;
        pp[row * N + ncol[t2]] = (_Float16)acc[mt][t2][i];
      }
}

extern "C" void kernel_launch(void* const* d_in, const int* in_sizes, int n_in,
                              void* d_out, int out_size, void* d_ws, size_t ws_size,
                              hipStream_t stream) {
  const float* x    = (const float*)d_in[0];
  const int* qw     = (const int*)d_in[1];
  const int* qz     = (const int*)d_in[2];
  const float* sc   = (const float*)d_in[3];   // fp16 values delivered as f32
  const float* bias = (const float*)d_in[4];   // fp16 values delivered as f32
  float* out        = (float*)d_out;

  _Float16* partial = (_Float16*)d_ws;                       // 16 x 352256 f16 = 11.3 MB
  _Float16* xh      = partial + (long)KSPLIT * OUT_ELEMS;    // +256 KB

  cvt_x_kernel<<<dim3((32 * K) / (256 * 8)), 256, 0, stream>>>(x, xh);
  awq_gemm_kernel<<<dim3(N / BN, KSPLIT), 256, 0, stream>>>(qw, qz, sc, xh, partial);
  reduce_kernel<<<dim3(OUT_ELEMS / (256 * 8)), 256, 0, stream>>>(partial, bias, out);
}

// Round 19
// 22.410 us; speedup vs baseline: 1.4838x; 1.4838x over previous
//
#include <hip/hip_runtime.h>
#include <hip/hip_fp16.h>

typedef _Float16 f16x8 __attribute__((ext_vector_type(8)));
typedef _Float16 f16x2 __attribute__((ext_vector_type(2)));
typedef float f32x4 __attribute__((ext_vector_type(4)));

namespace {
constexpr int K = 4096;
constexpr int N = 11008;
constexpr int NC = N / 8;            // 1376 packed words per K-row
constexpr int KSPLIT = 16;           // 256-deep K slices (2 quant groups)
constexpr int SLICE_K = K / KSPLIT;  // 256
constexpr int BN = 128;              // output columns per block (8 waves x 16)
constexpr int BK = 32;               // K rows per MFMA step
constexpr int NT = SLICE_K / BK;     // 8 steps
constexpr int QS = SLICE_K + 4;      // q LDS col stride, words (260)
constexpr int XSH = 272;             // x LDS row stride, halfs (16B-aligned rows)
constexpr int OUT_ELEMS = 32 * N;    // 352256
}

// sum 16 f16 K-slice partials + bias -> out (8 outputs per thread)
__global__ void reduce_kernel(const _Float16* __restrict__ partial,
                              const float* __restrict__ bias,
                              float* __restrict__ out) {
  const int idx = (blockIdx.x * 256 + threadIdx.x) * 8;   // 172 blocks exact
  const int n = idx % N;                                  // N, idx multiples of 8
  const float4 b0 = *reinterpret_cast<const float4*>(bias + n);
  const float4 b1 = *reinterpret_cast<const float4*>(bias + n + 4);
  float a[8] = {b0.x, b0.y, b0.z, b0.w, b1.x, b1.y, b1.z, b1.w};
#pragma unroll
  for (int s = 0; s < KSPLIT; ++s) {
    const f16x8 p = *reinterpret_cast<const f16x8*>(partial + (long)s * OUT_ELEMS + idx);
#pragma unroll
    for (int j = 0; j < 8; ++j) a[j] += (float)p[j];
  }
  float4 o0 = {a[0], a[1], a[2], a[3]}, o1 = {a[4], a[5], a[6], a[7]};
  *reinterpret_cast<float4*>(out + idx)     = o0;
  *reinterpret_cast<float4*>(out + idx + 4) = o1;
}

// 512-thread (8-wave) GEMM: one-shot coalesced staging of q (16.6KB) and
// x f32->f16 (17.4KB) into LDS, ONE barrier, 8 MFMA steps with zero VMEM.
// Each wave owns 16 output columns -> half the per-wave VALU of the 4-wave
// version; 4 blocks/CU x 8 waves = 8 waves/SIMD (2x r17 occupancy).
__global__ __launch_bounds__(512, 8) void awq_gemm_kernel(
    const int* __restrict__ qw, const int* __restrict__ qz,
    const float* __restrict__ sc, const float* __restrict__ x,
    _Float16* __restrict__ partial)
{
  __shared__ int lqs[16 * QS];          // q tile, col-major [word-col][k]
  __shared__ _Float16 lxh[32 * XSH];    // x tile f16, [row][k]

  const int tid  = threadIdx.x;
  const int lane = tid & 63;
  const int wid  = tid >> 6;      // wave 0..7
  const int kq   = lane >> 4;     // 0..3  (k-quarter within MFMA frag)
  const int c16  = lane & 15;     // fragment row/col index

  const int bx = blockIdx.x, by = blockIdx.y;
  const int n0 = bx * BN;
  const int c0 = n0 >> 3;

  // AWQ nibble shift for col (n&7): 4*AWQ_ORDER[n&7], order [0,4,1,5,2,6,3,7]
  const int j7 = c16 & 7;
  const int sh = ((j7 >> 1) | ((j7 & 1) << 2)) << 2;

  const int ncol  = n0 + wid * 16 + c16;   // this lane's output column
  const int cglob = ncol >> 3;             // packed word column (global)
  const int cloc  = wid * 2 + (c16 >> 3);  // word-col within LDS tile (0..15)

  const int kbeg = by * SLICE_K;
  const int g0   = kbeg >> 7;     // first of 2 quant groups in this slice

  // ---- issue ALL global loads up front ----
  // q: thread -> (k-row kr, word-group wg); 2 rounds of 128 rows.
  // Wave-instr: 16 rows x 64B contiguous = 16 fully-used lines.
  const int kr = tid >> 2;        // 0..127
  const int wg = tid & 3;         // 0..3 -> words wg*4..wg*4+3
  const int4 qv0 = *reinterpret_cast<const int4*>(
      qw + (long)(kbeg + kr) * NC + c0 + wg * 4);
  const int4 qv1 = *reinterpret_cast<const int4*>(
      qw + (long)(kbeg + 128 + kr) * NC + c0 + wg * 4);

  // x: thread -> (row xm, 16-half chunk xo); f32 loads, cvt during store.
  const int xm = tid >> 4;        // 0..31
  const int xo = tid & 15;        // 0..15
  const float* xrow = x + (long)xm * K + kbeg + xo * 16;
  const float4 xa = *reinterpret_cast<const float4*>(xrow);
  const float4 xb = *reinterpret_cast<const float4*>(xrow + 4);
  const float4 xc = *reinterpret_cast<const float4*>(xrow + 8);
  const float4 xd = *reinterpret_cast<const float4*>(xrow + 12);

  // group scalars -> packed f16 constants (while loads are in flight)
  f16x2 s2[2], mz2[2];            // [group]
#pragma unroll
  for (int g = 0; g < 2; ++g) {
    const int zq = qz[(g0 + g) * NC + cglob];
    const _Float16 s16 = (_Float16)sc[(g0 + g) * N + ncol];
    const _Float16 mz  = (_Float16)(-(float)(1024 + ((zq >> sh) & 15)));
    s2[g][0] = s16; s2[g][1] = s16;
    mz2[g][0] = mz; mz2[g][1] = mz;
  }

  // ---- LDS writes ----
  lqs[(wg * 4 + 0) * QS + kr] = qv0.x;
  lqs[(wg * 4 + 1) * QS + kr] = qv0.y;
  lqs[(wg * 4 + 2) * QS + kr] = qv0.z;
  lqs[(wg * 4 + 3) * QS + kr] = qv0.w;
  lqs[(wg * 4 + 0) * QS + 128 + kr] = qv1.x;
  lqs[(wg * 4 + 1) * QS + 128 + kr] = qv1.y;
  lqs[(wg * 4 + 2) * QS + 128 + kr] = qv1.z;
  lqs[(wg * 4 + 3) * QS + 128 + kr] = qv1.w;
  {
    union { f16x2 h2[4]; f16x8 h8; } u0, u1;
    u0.h2[0] = __builtin_bit_cast(f16x2, __builtin_amdgcn_cvt_pkrtz(xa.x, xa.y));
    u0.h2[1] = __builtin_bit_cast(f16x2, __builtin_amdgcn_cvt_pkrtz(xa.z, xa.w));
    u0.h2[2] = __builtin_bit_cast(f16x2, __builtin_amdgcn_cvt_pkrtz(xb.x, xb.y));
    u0.h2[3] = __builtin_bit_cast(f16x2, __builtin_amdgcn_cvt_pkrtz(xb.z, xb.w));
    u1.h2[0] = __builtin_bit_cast(f16x2, __builtin_amdgcn_cvt_pkrtz(xc.x, xc.y));
    u1.h2[1] = __builtin_bit_cast(f16x2, __builtin_amdgcn_cvt_pkrtz(xc.z, xc.w));
    u1.h2[2] = __builtin_bit_cast(f16x2, __builtin_amdgcn_cvt_pkrtz(xd.x, xd.y));
    u1.h2[3] = __builtin_bit_cast(f16x2, __builtin_amdgcn_cvt_pkrtz(xd.z, xd.w));
    _Float16* dst = &lxh[xm * XSH + xo * 16];
    *reinterpret_cast<f16x8*>(dst)     = u0.h8;
    *reinterpret_cast<f16x8*>(dst + 8) = u1.h8;
  }

  __syncthreads();               // the ONLY barrier

  f32x4 acc[2] = {};             // [m-tile]

#pragma unroll
  for (int t = 0; t < NT; ++t) {
    const int g = t >> 2;        // quant group (4 steps/group)
    const f16x8 a0 = *reinterpret_cast<const f16x8*>(&lxh[c16 * XSH + t * BK + kq * 8]);
    const f16x8 a1 = *reinterpret_cast<const f16x8*>(&lxh[(c16 + 16) * XSH + t * BK + kq * 8]);

    const int base = cloc * QS + t * BK + kq * 8;
    f16x8 b;
#pragma unroll
    for (int half = 0; half < 2; ++half) {
      const int4 q4 = *reinterpret_cast<const int4*>(&lqs[base + 4 * half]);
      const unsigned v0 = __builtin_amdgcn_ubfe((unsigned)q4.x, sh, 4);
      const unsigned v1 = __builtin_amdgcn_ubfe((unsigned)q4.y, sh, 4);
      const unsigned v2 = __builtin_amdgcn_ubfe((unsigned)q4.z, sh, 4);
      const unsigned v3 = __builtin_amdgcn_ubfe((unsigned)q4.w, sh, 4);
      const f16x2 h01 = __builtin_bit_cast(f16x2, (v0 | (v1 << 16)) | 0x64006400u);
      const f16x2 h23 = __builtin_bit_cast(f16x2, (v2 | (v3 << 16)) | 0x64006400u);
      const f16x2 w01 = (h01 + mz2[g]) * s2[g];   // exact (v-z), 1 rounding
      const f16x2 w23 = (h23 + mz2[g]) * s2[g];
      b[4 * half]     = w01[0];
      b[4 * half + 1] = w01[1];
      b[4 * half + 2] = w23[0];
      b[4 * half + 3] = w23[1];
    }
    acc[0] = __builtin_amdgcn_mfma_f32_16x16x32_f16(a0, b, acc[0], 0, 0, 0);
    acc[1] = __builtin_amdgcn_mfma_f32_16x16x32_f16(a1, b, acc[1], 0, 0, 0);
  }

  // ---- epilogue: f16 partials, plain stores ----
  _Float16* pp = partial + (long)by * OUT_ELEMS;
#pragma unroll
  for (int mt = 0; mt < 2; ++mt)
#pragma unroll
    for (int i = 0; i < 4; ++i) {
      const int row = mt * 16 + kq * 4 + i;
      pp[row * N + ncol] = (_Float16)acc[mt][i];
    }
}

extern "C" void kernel_launch(void* const* d_in, const int* in_sizes, int n_in,
                              void* d_out, int out_size, void* d_ws, size_t ws_size,
                              hipStream_t stream) {
  const float* x    = (const float*)d_in[0];
  const int* qw     = (const int*)d_in[1];
  const int* qz     = (const int*)d_in[2];
  const float* sc   = (const float*)d_in[3];   // fp16 values delivered as f32
  const float* bias = (const float*)d_in[4];   // fp16 values delivered as f32
  float* out        = (float*)d_out;

  _Float16* partial = (_Float16*)d_ws;         // 16 x 352256 f16 = 11.3 MB

  awq_gemm_kernel<<<dim3(N / BN, KSPLIT), 512, 0, stream>>>(qw, qz, sc, x, partial);
  reduce_kernel<<<dim3(OUT_ELEMS / (256 * 8)), 256, 0, stream>>>(partial, bias, out);
}

// Round 20
// 21.215 us; speedup vs baseline: 1.5674x; 1.0563x over previous
//
#include <hip/hip_runtime.h>
#include <hip/hip_fp16.h>

typedef _Float16 f16x8 __attribute__((ext_vector_type(8)));
typedef _Float16 f16x2 __attribute__((ext_vector_type(2)));
typedef float f32x4 __attribute__((ext_vector_type(4)));

namespace {
constexpr int K = 4096;
constexpr int N = 11008;
constexpr int NC = N / 8;            // 1376 packed words per K-row
constexpr int KSPLIT = 16;           // 256-deep K slices (2 quant groups)
constexpr int SLICE_K = K / KSPLIT;  // 256
constexpr int BN = 128;              // output columns per tile (8 waves x 16)
constexpr int BK = 32;               // K rows per MFMA step
constexpr int NT = SLICE_K / BK;     // 8 steps
constexpr int QS = SLICE_K + 4;      // q LDS col stride, words (260)
constexpr int XSH = 272;             // x LDS row stride, halfs
constexpr int OUT_ELEMS = 32 * N;    // 352256
}

// sum 16 f16 K-slice partials + bias -> out (8 outputs per thread)
__global__ void reduce_kernel(const _Float16* __restrict__ partial,
                              const float* __restrict__ bias,
                              float* __restrict__ out) {
  const int idx = (blockIdx.x * 256 + threadIdx.x) * 8;   // 172 blocks exact
  const int n = idx % N;
  const float4 b0 = *reinterpret_cast<const float4*>(bias + n);
  const float4 b1 = *reinterpret_cast<const float4*>(bias + n + 4);
  float a[8] = {b0.x, b0.y, b0.z, b0.w, b1.x, b1.y, b1.z, b1.w};
#pragma unroll
  for (int s = 0; s < KSPLIT; ++s) {
    const f16x8 p = *reinterpret_cast<const f16x8*>(partial + (long)s * OUT_ELEMS + idx);
#pragma unroll
    for (int j = 0; j < 8; ++j) a[j] += (float)p[j];
  }
  float4 o0 = {a[0], a[1], a[2], a[3]}, o1 = {a[4], a[5], a[6], a[7]};
  *reinterpret_cast<float4*>(out + idx)     = o0;
  *reinterpret_cast<float4*>(out + idx + 4) = o1;
}

// 2-tile pipelined 8-wave GEMM: x staged ONCE per block; q for tile1 issued
// before tile0's compute (HBM latency hidden under compute, T14 pattern).
__global__ __launch_bounds__(512, 8) void awq_gemm_kernel(
    const int* __restrict__ qw, const int* __restrict__ qz,
    const float* __restrict__ sc, const float* __restrict__ x,
    _Float16* __restrict__ partial)
{
  __shared__ int lqs[16 * QS];          // q tile, col-major [word-col][k]
  __shared__ _Float16 lxh[32 * XSH];    // x tile f16, [row][k]

  const int tid  = threadIdx.x;
  const int lane = tid & 63;
  const int wid  = tid >> 6;      // wave 0..7
  const int kq   = lane >> 4;     // 0..3
  const int c16  = lane & 15;

  const int by  = blockIdx.y;
  const int bx0 = blockIdx.x * 2; // tiles bx0, bx0+1 (86 = 43*2)

  // AWQ nibble shift for col (n&7): 4*AWQ_ORDER[n&7], order [0,4,1,5,2,6,3,7]
  const int j7 = c16 & 7;
  const int sh = ((j7 >> 1) | ((j7 & 1) << 2)) << 2;

  const int cloc = wid * 2 + (c16 >> 3);  // LDS word-col 0..15 (tile-invariant)
  const int kbeg = by * SLICE_K;
  const int g0   = kbeg >> 7;             // first of 2 quant groups

  int ncol[2], cglob[2];
#pragma unroll
  for (int tt = 0; tt < 2; ++tt) {
    ncol[tt]  = (bx0 + tt) * BN + wid * 16 + c16;
    cglob[tt] = ncol[tt] >> 3;
  }

  // ---- staging geometry ----
  const int kr = tid >> 2;        // 0..127
  const int wg = tid & 3;         // word group
  const int xm = tid >> 4;        // 0..31
  const int xo = tid & 15;        // 0..15

  // issue x loads (once per block)
  const float* xrow = x + (long)xm * K + kbeg + xo * 16;
  const float4 xa = *reinterpret_cast<const float4*>(xrow);
  const float4 xb = *reinterpret_cast<const float4*>(xrow + 4);
  const float4 xc = *reinterpret_cast<const float4*>(xrow + 8);
  const float4 xd = *reinterpret_cast<const float4*>(xrow + 12);

  // issue q tile0 loads
  const int c00 = bx0 * (BN / 8);
  const int4 q0a = *reinterpret_cast<const int4*>(qw + (long)(kbeg + kr) * NC + c00 + wg * 4);
  const int4 q0b = *reinterpret_cast<const int4*>(qw + (long)(kbeg + 128 + kr) * NC + c00 + wg * 4);

  // group scalars for BOTH tiles (in flight with the above)
  f16x2 s2[2][2], mz2[2][2];      // [tile][group]
#pragma unroll
  for (int tt = 0; tt < 2; ++tt)
#pragma unroll
    for (int g = 0; g < 2; ++g) {
      const int zq = qz[(g0 + g) * NC + cglob[tt]];
      const _Float16 s16 = (_Float16)sc[(g0 + g) * N + ncol[tt]];
      const _Float16 mz  = (_Float16)(-(float)(1024 + ((zq >> sh) & 15)));
      s2[tt][g][0] = s16; s2[tt][g][1] = s16;
      mz2[tt][g][0] = mz; mz2[tt][g][1] = mz;
    }

  // x convert + LDS write
  {
    union { f16x2 h2[4]; f16x8 h8; } u0, u1;
    u0.h2[0] = __builtin_bit_cast(f16x2, __builtin_amdgcn_cvt_pkrtz(xa.x, xa.y));
    u0.h2[1] = __builtin_bit_cast(f16x2, __builtin_amdgcn_cvt_pkrtz(xa.z, xa.w));
    u0.h2[2] = __builtin_bit_cast(f16x2, __builtin_amdgcn_cvt_pkrtz(xb.x, xb.y));
    u0.h2[3] = __builtin_bit_cast(f16x2, __builtin_amdgcn_cvt_pkrtz(xb.z, xb.w));
    u1.h2[0] = __builtin_bit_cast(f16x2, __builtin_amdgcn_cvt_pkrtz(xc.x, xc.y));
    u1.h2[1] = __builtin_bit_cast(f16x2, __builtin_amdgcn_cvt_pkrtz(xc.z, xc.w));
    u1.h2[2] = __builtin_bit_cast(f16x2, __builtin_amdgcn_cvt_pkrtz(xd.x, xd.y));
    u1.h2[3] = __builtin_bit_cast(f16x2, __builtin_amdgcn_cvt_pkrtz(xd.z, xd.w));
    _Float16* dst = &lxh[xm * XSH + xo * 16];
    *reinterpret_cast<f16x8*>(dst)     = u0.h8;
    *reinterpret_cast<f16x8*>(dst + 8) = u1.h8;
  }

  // q tile0 -> LDS (compiler waits its vmcnt)
  lqs[(wg * 4 + 0) * QS + kr] = q0a.x;
  lqs[(wg * 4 + 1) * QS + kr] = q0a.y;
  lqs[(wg * 4 + 2) * QS + kr] = q0a.z;
  lqs[(wg * 4 + 3) * QS + kr] = q0a.w;
  lqs[(wg * 4 + 0) * QS + 128 + kr] = q0b.x;
  lqs[(wg * 4 + 1) * QS + 128 + kr] = q0b.y;
  lqs[(wg * 4 + 2) * QS + 128 + kr] = q0b.z;
  lqs[(wg * 4 + 3) * QS + 128 + kr] = q0b.w;

  // issue q tile1 loads NOW -> in flight across tile0's whole compute
  const int c01 = (bx0 + 1) * (BN / 8);
  const int4 q1a = *reinterpret_cast<const int4*>(qw + (long)(kbeg + kr) * NC + c01 + wg * 4);
  const int4 q1b = *reinterpret_cast<const int4*>(qw + (long)(kbeg + 128 + kr) * NC + c01 + wg * 4);

  __syncthreads();

  _Float16* pp = partial + (long)by * OUT_ELEMS;

  // ---- compute one staged tile (reads lqs/lxh), store partials ----
  auto compute_tile = [&](int tt) {
    f32x4 acc[2] = {};
#pragma unroll
    for (int t = 0; t < NT; ++t) {
      const int g = t >> 2;
      const f16x8 a0 = *reinterpret_cast<const f16x8*>(&lxh[c16 * XSH + t * BK + kq * 8]);
      const f16x8 a1 = *reinterpret_cast<const f16x8*>(&lxh[(c16 + 16) * XSH + t * BK + kq * 8]);
      const int base = cloc * QS + t * BK + kq * 8;
      f16x8 b;
#pragma unroll
      for (int half = 0; half < 2; ++half) {
        const int4 q4 = *reinterpret_cast<const int4*>(&lqs[base + 4 * half]);
        const unsigned v0 = __builtin_amdgcn_ubfe((unsigned)q4.x, sh, 4);
        const unsigned v1 = __builtin_amdgcn_ubfe((unsigned)q4.y, sh, 4);
        const unsigned v2 = __builtin_amdgcn_ubfe((unsigned)q4.z, sh, 4);
        const unsigned v3 = __builtin_amdgcn_ubfe((unsigned)q4.w, sh, 4);
        const f16x2 h01 = __builtin_bit_cast(f16x2, (v0 | (v1 << 16)) | 0x64006400u);
        const f16x2 h23 = __builtin_bit_cast(f16x2, (v2 | (v3 << 16)) | 0x64006400u);
        const f16x2 w01 = (h01 + mz2[tt][g]) * s2[tt][g];   // exact (v-z), 1 rnd
        const f16x2 w23 = (h23 + mz2[tt][g]) * s2[tt][g];
        b[4 * half]     = w01[0];
        b[4 * half + 1] = w01[1];
        b[4 * half + 2] = w23[0];
        b[4 * half + 3] = w23[1];
      }
      acc[0] = __builtin_amdgcn_mfma_f32_16x16x32_f16(a0, b, acc[0], 0, 0, 0);
      acc[1] = __builtin_amdgcn_mfma_f32_16x16x32_f16(a1, b, acc[1], 0, 0, 0);
    }
#pragma unroll
    for (int mt = 0; mt < 2; ++mt)
#pragma unroll
      for (int i = 0; i < 4; ++i) {
        const int row = mt * 16 + kq * 4 + i;
        pp[row * N + ncol[tt]] = (_Float16)acc[mt][i];
      }
  };

  compute_tile(0);

  __syncthreads();               // all waves done reading tile0's lqs

  // q tile1 -> LDS (vmcnt long satisfied: issued before tile0 compute)
  lqs[(wg * 4 + 0) * QS + kr] = q1a.x;
  lqs[(wg * 4 + 1) * QS + kr] = q1a.y;
  lqs[(wg * 4 + 2) * QS + kr] = q1a.z;
  lqs[(wg * 4 + 3) * QS + kr] = q1a.w;
  lqs[(wg * 4 + 0) * QS + 128 + kr] = q1b.x;
  lqs[(wg * 4 + 1) * QS + 128 + kr] = q1b.y;
  lqs[(wg * 4 + 2) * QS + 128 + kr] = q1b.z;
  lqs[(wg * 4 + 3) * QS + 128 + kr] = q1b.w;

  __syncthreads();

  compute_tile(1);
}

extern "C" void kernel_launch(void* const* d_in, const int* in_sizes, int n_in,
                              void* d_out, int out_size, void* d_ws, size_t ws_size,
                              hipStream_t stream) {
  const float* x    = (const float*)d_in[0];
  const int* qw     = (const int*)d_in[1];
  const int* qz     = (const int*)d_in[2];
  const float* sc   = (const float*)d_in[3];   // fp16 values delivered as f32
  const float* bias = (const float*)d_in[4];   // fp16 values delivered as f32
  float* out        = (float*)d_out;

  _Float16* partial = (_Float16*)d_ws;         // 16 x 352256 f16 = 11.3 MB

  awq_gemm_kernel<<<dim3(43, KSPLIT), 512, 0, stream>>>(qw, qz, sc, x, partial);
  reduce_kernel<<<dim3(OUT_ELEMS / (256 * 8)), 256, 0, stream>>>(partial, bias, out);
}

// Round 21
// 20.884 us; speedup vs baseline: 1.5922x; 1.0158x over previous
//
#include <hip/hip_runtime.h>
#include <hip/hip_fp16.h>

typedef _Float16 f16x8 __attribute__((ext_vector_type(8)));
typedef _Float16 f16x2 __attribute__((ext_vector_type(2)));
typedef float f32x4 __attribute__((ext_vector_type(4)));

namespace {
constexpr int K = 4096;
constexpr int N = 11008;
constexpr int NC = N / 8;            // 1376 packed words per K-row
constexpr int KSPLIT = 16;           // 256-deep K slices (2 quant groups)
constexpr int SLICE_K = K / KSPLIT;  // 256
constexpr int BXW = 32;              // word-cols per block -> 128B/row contiguous
constexpr int BK = 32;               // K rows per MFMA step
constexpr int NT = SLICE_K / BK;     // 8 steps
constexpr int QS = SLICE_K + 4;      // q LDS col stride, words (260)
constexpr int XSH = 272;             // x LDS row stride, halfs
constexpr int OUT_ELEMS = 32 * N;    // 352256
}

// sum 16 f16 K-slice partials + bias -> out (8 outputs per thread)
__global__ void reduce_kernel(const _Float16* __restrict__ partial,
                              const float* __restrict__ bias,
                              float* __restrict__ out) {
  const int idx = (blockIdx.x * 256 + threadIdx.x) * 8;   // 172 blocks exact
  const int n = idx % N;
  const float4 b0 = *reinterpret_cast<const float4*>(bias + n);
  const float4 b1 = *reinterpret_cast<const float4*>(bias + n + 4);
  float a[8] = {b0.x, b0.y, b0.z, b0.w, b1.x, b1.y, b1.z, b1.w};
#pragma unroll
  for (int s = 0; s < KSPLIT; ++s) {
    const f16x8 p = *reinterpret_cast<const f16x8*>(partial + (long)s * OUT_ELEMS + idx);
#pragma unroll
    for (int j = 0; j < 8; ++j) a[j] += (float)p[j];
  }
  float4 o0 = {a[0], a[1], a[2], a[3]}, o1 = {a[4], a[5], a[6], a[7]};
  *reinterpret_cast<float4*>(out + idx)     = o0;
  *reinterpret_cast<float4*>(out + idx + 4) = o1;
}

// 512-thread / 8-wave GEMM, 256 output cols per block: each qweight row is
// read as a 128B contiguous run (2x DRAM granule vs 64B before). One-shot
// staging of q (33KB) + x f32->f16 (17.4KB), ONE barrier, zero VMEM in loop.
__global__ __launch_bounds__(512, 4) void awq_gemm_kernel(
    const int* __restrict__ qw, const int* __restrict__ qz,
    const float* __restrict__ sc, const float* __restrict__ x,
    _Float16* __restrict__ partial)
{
  __shared__ int lqs[BXW * QS];         // q tile, col-major [word-col][k]
  __shared__ _Float16 lxh[32 * XSH];    // x tile f16, [row][k]

  const int tid  = threadIdx.x;
  const int lane = tid & 63;
  const int wid  = tid >> 6;      // wave 0..7
  const int kq   = lane >> 4;     // 0..3
  const int c16  = lane & 15;

  const int bx = blockIdx.x, by = blockIdx.y;
  const int n0 = bx * (BXW * 8);  // 256 output cols per block
  const int c0 = bx * BXW;

  // AWQ nibble shift for col (n&7): 4*AWQ_ORDER[n&7], order [0,4,1,5,2,6,3,7]
  const int j7 = c16 & 7;
  const int sh = ((j7 >> 1) | ((j7 & 1) << 2)) << 2;

  int ncol[2], cglob[2], cloc[2];
#pragma unroll
  for (int t2 = 0; t2 < 2; ++t2) {
    ncol[t2]  = n0 + wid * 32 + t2 * 16 + c16;
    cglob[t2] = ncol[t2] >> 3;
    cloc[t2]  = wid * 4 + t2 * 2 + (c16 >> 3);   // local word-col 0..31
  }

  const int kbeg = by * SLICE_K;
  const int g0   = kbeg >> 7;     // first of 2 quant groups in this slice

  // ---- issue ALL global loads up front ----
  // q: thread -> (row qr, chunk qc); 4 rounds of 64 rows; 128B/row by 8 lanes.
  const int qr = tid >> 3;        // 0..63
  const int qc = tid & 7;         // 0..7 -> words qc*4..qc*4+3
  int4 qv[4];
#pragma unroll
  for (int rr = 0; rr < 4; ++rr)
    qv[rr] = *reinterpret_cast<const int4*>(
        qw + (long)(kbeg + rr * 64 + qr) * NC + c0 + qc * 4);

  // x: thread -> (row xm, 16-half chunk xo); f32 loads, cvt during store.
  const int xm = tid >> 4;        // 0..31
  const int xo = tid & 15;        // 0..15
  const float* xrow = x + (long)xm * K + kbeg + xo * 16;
  const float4 xa = *reinterpret_cast<const float4*>(xrow);
  const float4 xb = *reinterpret_cast<const float4*>(xrow + 4);
  const float4 xc = *reinterpret_cast<const float4*>(xrow + 8);
  const float4 xd = *reinterpret_cast<const float4*>(xrow + 12);

  // group scalars -> packed f16 constants (while loads are in flight)
  f16x2 s2[2][2], mz2[2][2];      // [group][n-tile]
#pragma unroll
  for (int g = 0; g < 2; ++g)
#pragma unroll
    for (int t2 = 0; t2 < 2; ++t2) {
      const int zq = qz[(g0 + g) * NC + cglob[t2]];
      const _Float16 s16 = (_Float16)sc[(g0 + g) * N + ncol[t2]];
      const _Float16 mz  = (_Float16)(-(float)(1024 + ((zq >> sh) & 15)));
      s2[g][t2][0] = s16; s2[g][t2][1] = s16;
      mz2[g][t2][0] = mz; mz2[g][t2][1] = mz;
    }

  // ---- LDS writes ----
#pragma unroll
  for (int rr = 0; rr < 4; ++rr) {
    const int r = rr * 64 + qr;
    lqs[(qc * 4 + 0) * QS + r] = qv[rr].x;
    lqs[(qc * 4 + 1) * QS + r] = qv[rr].y;
    lqs[(qc * 4 + 2) * QS + r] = qv[rr].z;
    lqs[(qc * 4 + 3) * QS + r] = qv[rr].w;
  }
  {
    union { f16x2 h2[4]; f16x8 h8; } u0, u1;
    u0.h2[0] = __builtin_bit_cast(f16x2, __builtin_amdgcn_cvt_pkrtz(xa.x, xa.y));
    u0.h2[1] = __builtin_bit_cast(f16x2, __builtin_amdgcn_cvt_pkrtz(xa.z, xa.w));
    u0.h2[2] = __builtin_bit_cast(f16x2, __builtin_amdgcn_cvt_pkrtz(xb.x, xb.y));
    u0.h2[3] = __builtin_bit_cast(f16x2, __builtin_amdgcn_cvt_pkrtz(xb.z, xb.w));
    u1.h2[0] = __builtin_bit_cast(f16x2, __builtin_amdgcn_cvt_pkrtz(xc.x, xc.y));
    u1.h2[1] = __builtin_bit_cast(f16x2, __builtin_amdgcn_cvt_pkrtz(xc.z, xc.w));
    u1.h2[2] = __builtin_bit_cast(f16x2, __builtin_amdgcn_cvt_pkrtz(xd.x, xd.y));
    u1.h2[3] = __builtin_bit_cast(f16x2, __builtin_amdgcn_cvt_pkrtz(xd.z, xd.w));
    _Float16* dst = &lxh[xm * XSH + xo * 16];
    *reinterpret_cast<f16x8*>(dst)     = u0.h8;
    *reinterpret_cast<f16x8*>(dst + 8) = u1.h8;
  }

  __syncthreads();               // the ONLY barrier

  f32x4 acc[2][2] = {};          // [m-tile][n-tile]

#pragma unroll
  for (int t = 0; t < NT; ++t) {
    const int g = t >> 2;        // quant group (4 steps/group)
    const f16x8 a0 = *reinterpret_cast<const f16x8*>(&lxh[c16 * XSH + t * BK + kq * 8]);
    const f16x8 a1 = *reinterpret_cast<const f16x8*>(&lxh[(c16 + 16) * XSH + t * BK + kq * 8]);

#pragma unroll
    for (int t2 = 0; t2 < 2; ++t2) {
      const int base = cloc[t2] * QS + t * BK + kq * 8;
      f16x8 b;
#pragma unroll
      for (int half = 0; half < 2; ++half) {
        const int4 q4 = *reinterpret_cast<const int4*>(&lqs[base + 4 * half]);
        const unsigned v0 = __builtin_amdgcn_ubfe((unsigned)q4.x, sh, 4);
        const unsigned v1 = __builtin_amdgcn_ubfe((unsigned)q4.y, sh, 4);
        const unsigned v2 = __builtin_amdgcn_ubfe((unsigned)q4.z, sh, 4);
        const unsigned v3 = __builtin_amdgcn_ubfe((unsigned)q4.w, sh, 4);
        const f16x2 h01 = __builtin_bit_cast(f16x2, (v0 | (v1 << 16)) | 0x64006400u);
        const f16x2 h23 = __builtin_bit_cast(f16x2, (v2 | (v3 << 16)) | 0x64006400u);
        const f16x2 w01 = (h01 + mz2[g][t2]) * s2[g][t2];   // exact (v-z), 1 rnd
        const f16x2 w23 = (h23 + mz2[g][t2]) * s2[g][t2];
        b[4 * half]     = w01[0];
        b[4 * half + 1] = w01[1];
        b[4 * half + 2] = w23[0];
        b[4 * half + 3] = w23[1];
      }
      acc[0][t2] = __builtin_amdgcn_mfma_f32_16x16x32_f16(a0, b, acc[0][t2], 0, 0, 0);
      acc[1][t2] = __builtin_amdgcn_mfma_f32_16x16x32_f16(a1, b, acc[1][t2], 0, 0, 0);
    }
  }

  // ---- epilogue: f16 partials, plain stores ----
  _Float16* pp = partial + (long)by * OUT_ELEMS;
#pragma unroll
  for (int mt = 0; mt < 2; ++mt)
#pragma unroll
    for (int t2 = 0; t2 < 2; ++t2)
#pragma unroll
      for (int i = 0; i < 4; ++i) {
        const int row = mt * 16 + kq * 4 + i;
        pp[row * N + ncol[t2]] = (_Float16)acc[mt][t2][i];
      }
}

extern "C" void kernel_launch(void* const* d_in, const int* in_sizes, int n_in,
                              void* d_out, int out_size, void* d_ws, size_t ws_size,
                              hipStream_t stream) {
  const float* x    = (const float*)d_in[0];
  const int* qw     = (const int*)d_in[1];
  const int* qz     = (const int*)d_in[2];
  const float* sc   = (const float*)d_in[3];   // fp16 values delivered as f32
  const float* bias = (const float*)d_in[4];   // fp16 values delivered as f32
  float* out        = (float*)d_out;

  _Float16* partial = (_Float16*)d_ws;         // 16 x 352256 f16 = 11.3 MB

  awq_gemm_kernel<<<dim3(NC / BXW, KSPLIT), 512, 0, stream>>>(qw, qz, sc, x, partial);
  reduce_kernel<<<dim3(OUT_ELEMS / (256 * 8)), 256, 0, stream>>>(partial, bias, out);
}